// Round 15
// baseline (103.860 us; speedup 1.0000x reference)
//
#include <hip/hip_runtime.h>
#include <stdint.h>

#define EMB 1024
#define HEADS 16
#define NB 2
#define NS 2048
#define HD 64
#define NTOK (NB*NS)          // 4096
#define KVBLK 128
#define QW 16                 // q rows per wave
#define SEXP2 0.04508421676368185f   // log2(e)/32, folded into prescaled Q

typedef __attribute__((ext_vector_type(8))) short short8;
typedef __attribute__((ext_vector_type(4))) float f32x4;
typedef __attribute__((ext_vector_type(4))) unsigned int u32x4;

// round-to-nearest-even f32 -> bf16 bits (epilogues / cvt only)
__device__ inline unsigned short f2bf(float f) {
  unsigned int x = __builtin_bit_cast(unsigned int, f);
  x += 0x7FFFu + ((x >> 16) & 1u);
  return (unsigned short)(x >> 16);
}

// HW packed f32x2 -> bf16x2 (RNE); no builtin on gfx950 (T12 recipe)
__device__ inline unsigned cvt_pk_bf16(float lo, float hi) {
  unsigned d;
  asm("v_cvt_pk_bf16_f32 %0, %1, %2" : "=v"(d) : "v"(lo), "v"(hi));
  return d;
}

// async global->LDS, 16B per lane; lds dest = wave-uniform base + lane*16
__device__ inline void gld16(const void* g, void* l) {
  __builtin_amdgcn_global_load_lds(
      (const __attribute__((address_space(1))) unsigned int*)g,
      (__attribute__((address_space(3))) unsigned int*)l, 16, 0, 0);
}

// x, wq, wu conversions in ONE launch (3-way range branch)
__global__ void cvt_bf16x3_kernel(const float* __restrict__ s0,
                                  unsigned short* __restrict__ d0, int n0,
                                  const float* __restrict__ s1,
                                  unsigned short* __restrict__ d1, int n1,
                                  const float* __restrict__ s2,
                                  unsigned short* __restrict__ d2, int n2) {
  int i = (blockIdx.x * blockDim.x + threadIdx.x) * 8;
  const float* s; unsigned short* d;
  if (i < n0) { s = s0 + i; d = d0 + i; }
  else if (i - n0 < n1) { s = s1 + (i - n0); d = d1 + (i - n0); }
  else if (i - n0 - n1 < n2) { s = s2 + (i - n0 - n1); d = d2 + (i - n0 - n1); }
  else return;
  float4 v0 = *reinterpret_cast<const float4*>(s);
  float4 v1 = *reinterpret_cast<const float4*>(s + 4);
  short8 o;
  o[0] = (short)f2bf(v0.x); o[1] = (short)f2bf(v0.y);
  o[2] = (short)f2bf(v0.z); o[3] = (short)f2bf(v0.w);
  o[4] = (short)f2bf(v1.x); o[5] = (short)f2bf(v1.y);
  o[6] = (short)f2bf(v1.z); o[7] = (short)f2bf(v1.w);
  *reinterpret_cast<short8*>(d) = o;
}

// per-slab transpose: src [32][2048][64] -> dst [32][64][2048], with the
// kv index PERMUTED within each 64-tile by invpi (matches in-register P
// packing of the swapped-QK^T path):
//   pv position p = kk*32 + g*8 + j  holds  kv = kk*32 + (j>>2)*16 + g*4 + (j&3)
//   invpi(p) = (p&32) | (((p>>2)&1)<<4) | (((p>>3)&3)<<2) | (p&3)
__global__ __launch_bounds__(256) void transpose_kernel(
    const unsigned short* __restrict__ src, unsigned short* __restrict__ dst) {
  __shared__ unsigned short t[64][72];   // pad: row stride 144B
  const int slab = blockIdx.y, kt = blockIdx.x;
  const unsigned short* s = src + ((size_t)slab * NS + kt * 64) * HD;
  unsigned short* d = dst + (size_t)slab * HD * NS + kt * 64;
  const int tid = threadIdx.x;
  #pragma unroll
  for (int c = 0; c < 2; ++c) {
    int idx = c * 256 + tid;             // 0..511
    int row = idx >> 3, col = (idx & 7) * 8;
    short8 v = *reinterpret_cast<const short8*>(s + row * HD + col);
    *reinterpret_cast<short8*>(&t[row][col]) = v;
  }
  __syncthreads();
  #pragma unroll
  for (int c = 0; c < 2; ++c) {
    int idx = c * 256 + tid;
    int drow = idx >> 3, col = (idx & 7) * 8;
    short8 v;
    #pragma unroll
    for (int j = 0; j < 8; ++j) {
      int p = col + j;
      int kv = (p & 32) | (((p >> 2) & 1) << 4) | (((p >> 3) & 3) << 2) | (p & 3);
      v[j] = t[kv][drow];
    }
    *reinterpret_cast<short8*>(d + (size_t)drow * NS + col) = v;
  }
}

// C[M][N] = A[M][K] * Bw[N][K]^T + bias[N].  BM=64 BN=64 BK=64, 128 threads
// (2 waves, each 32x64 out -> af reused over 4 n-frags: 12 reads : 16 MFMAs).
// Grid 1024 = 4 blocks/CU, 8 waves/CU. dbuf, global_load_lds staging
// (linear dest + inverse-swizzled source), 2-phase.
// Optional second output: Qscaled = bf16((C)*SEXP2), single-rounded.
template<bool OUT_BF16>
__global__ __launch_bounds__(128) void gemm_bt_kernel(
    const unsigned short* __restrict__ A,
    const unsigned short* __restrict__ Bw,
    const float* __restrict__ bias,
    void* __restrict__ Cout,
    unsigned short* __restrict__ Qscaled,
    int M, int N, int K) {
  __shared__ __align__(16) unsigned short As[2][64 * 64];
  __shared__ __align__(16) unsigned short Bs[2][64 * 64];
  const int tid = threadIdx.x;
  const int lane = tid & 63;
  const int wave = tid >> 6;             // 0/1
  const int g = lane >> 4, r = lane & 15;
  const int brow = blockIdx.y * 64;
  const int bcol = blockIdx.x * 64;

  const f32x4 zf = {0.f, 0.f, 0.f, 0.f};
  f32x4 acc[2][4];
  #pragma unroll
  for (int m = 0; m < 2; ++m)
    #pragma unroll
    for (int n = 0; n < 4; ++n) acc[m][n] = zf;

  auto stage = [&](int bb, int k0) {
    #pragma unroll
    for (int i = 0; i < 4; ++i) {            // A: 64x64 = 8KB = 4 issues/wave
      int base = (wave * 4 + i) * 1024;
      int L = base + lane * 16;
      int row = L >> 7, lsl = ((L >> 4) & 7) ^ (row & 7);
      gld16((const char*)A + ((size_t)(brow + row) * K + k0) * 2 + lsl * 16,
            (char*)&As[bb][0] + base);
    }
    #pragma unroll
    for (int i = 0; i < 4; ++i) {            // B: 64x64 = 8KB = 4 issues/wave
      int base = (wave * 4 + i) * 1024;
      int L = base + lane * 16;
      int row = L >> 7, lsl = ((L >> 4) & 7) ^ (row & 7);
      gld16((const char*)Bw + ((size_t)(bcol + row) * K + k0) * 2 + lsl * 16,
            (char*)&Bs[bb][0] + base);
    }
  };

  stage(0, 0);
  int cur = 0;
  for (int k0 = 0; k0 < K; k0 += 64) {
    __syncthreads();                          // drains prev stage (vmcnt)
    if (k0 + 64 < K) stage(cur ^ 1, k0 + 64);
    const char* Ac = (const char*)&As[cur][0];
    const char* Bc = (const char*)&Bs[cur][0];
    short8 af[2][2], bfr[4][2];
    #pragma unroll
    for (int m = 0; m < 2; ++m) {
      int row = wave * 32 + m * 16 + r;
      #pragma unroll
      for (int kk = 0; kk < 2; ++kk)
        af[m][kk] = *reinterpret_cast<const short8*>(
            Ac + row * 128 + ((kk * 64 + g * 16) ^ ((row & 7) << 4)));
    }
    #pragma unroll
    for (int n = 0; n < 4; ++n) {
      int row = n * 16 + r;
      #pragma unroll
      for (int kk = 0; kk < 2; ++kk)
        bfr[n][kk] = *reinterpret_cast<const short8*>(
            Bc + row * 128 + ((kk * 64 + g * 16) ^ ((row & 7) << 4)));
    }
    #pragma unroll
    for (int kk = 0; kk < 2; ++kk)
      #pragma unroll
      for (int m = 0; m < 2; ++m)
        #pragma unroll
        for (int n = 0; n < 4; ++n)
          acc[m][n] = __builtin_amdgcn_mfma_f32_16x16x32_bf16(af[m][kk], bfr[n][kk], acc[m][n], 0, 0, 0);
    cur ^= 1;
  }

  #pragma unroll
  for (int n = 0; n < 4; ++n) {
    int col = bcol + n * 16 + r;
    float bv = bias[col];
    #pragma unroll
    for (int m = 0; m < 2; ++m) {
      #pragma unroll
      for (int reg = 0; reg < 4; ++reg) {
        int row = brow + wave * 32 + m * 16 + g * 4 + reg;
        float v = acc[m][n][reg] + bv;
        if (OUT_BF16)
          ((unsigned short*)Cout)[(size_t)row * N + col] = f2bf(v);
        else
          ((float*)Cout)[(size_t)row * N + col] = v;
        if (Qscaled)
          Qscaled[(size_t)row * N + col] = f2bf(v * SEXP2);
      }
    }
  }
}

// Flash attention (R14 compute body, KVBLK=128 = two R14 iterations per
// barrier: 16 syncthreads instead of 32). Q=K=V = contiguous slab [NS][HD];
// Vt pre-transposed and pi-permuted. 8 waves x 16 q-rows (128 q-rows/block);
// no-max softmax (prescaled Q); SWAPPED QK^T so P packs in-register for PV.
// V LDS rows are 256B -> 16-slot swizzle key (row&15)<<4 on stage AND read.
// Grid: 1-D 512 (16 qtiles x 32 slabs), slab-grouped XCD swizzle.
__global__ __launch_bounds__(512) void attn_kernel(
    const unsigned short* __restrict__ qb,
    const unsigned short* __restrict__ qsb,
    const unsigned short* __restrict__ vtb,
    unsigned short* __restrict__ ob) {
  const int bid = blockIdx.x;            // 0..511
  const int xcd = bid & 7, idx = bid >> 3;   // idx 0..63
  const int slab = xcd * 4 + (idx >> 4);
  const int qtile = idx & 15;            // 128 q-rows per block
  const unsigned short* Qs = qb + (size_t)slab * NS * HD;
  const unsigned short* Qss = qsb + (size_t)slab * NS * HD;  // prescaled
  const unsigned short* Vts = vtb + (size_t)slab * HD * NS;  // [64][2048] pi-perm
  unsigned short* Os = ob + (size_t)slab * NS * HD;
  const int tid = threadIdx.x;
  const int lane = tid & 63;
  const int wave = tid >> 6;             // 0..7
  const int g = lane >> 4, r = lane & 15;
  const int qrow0 = qtile * 128 + wave * QW;
  const int rkey = (r & 7) << 4;         // K-side swizzle (128B rows)
  const int vkey = r << 4;               // V-side swizzle (256B rows)

  __shared__ __align__(16) unsigned short K_lds[2][KVBLK * HD];   // [kv][64] swz
  __shared__ __align__(16) unsigned short Vt_lds[2][HD * KVBLK];  // [d][pi-kv] swz

  // 16KB per tensor per tile; 8 waves x 2 gld16 each
  auto stage = [&](int bb, int kt) {
    const char* Kg = (const char*)Qs + (size_t)kt * (KVBLK * HD * 2);  // 16KB
    const char* Vg = (const char*)Vts + (size_t)kt * (KVBLK * 2);     // col off
    #pragma unroll
    for (int i = 0; i < 2; ++i) {
      int base = (wave + i * 8) * 1024;
      int L = base + lane * 16;
      int krow = L >> 7, klsl = ((L >> 4) & 7) ^ (krow & 7);
      gld16(Kg + krow * 128 + klsl * 16, (char*)&K_lds[bb][0] + base);
      int vrow = L >> 8, vlsl = ((L >> 4) & 15) ^ (vrow & 15);
      gld16(Vg + (size_t)vrow * (NS * 2) + vlsl * 16, (char*)&Vt_lds[bb][0] + base);
    }
  };

  // Q fragments from the prescaled buffer; B operand of swapped QK^T:
  // col q = r, k d = kk*32 + g*8..+7
  short8 aq[2];
  #pragma unroll
  for (int kk = 0; kk < 2; ++kk)
    aq[kk] = *reinterpret_cast<const short8*>(
        &Qss[(size_t)(qrow0 + r) * HD + kk * 32 + g * 8]);

  const f32x4 zf = {0.f, 0.f, 0.f, 0.f};
  f32x4 o_acc[4];
  float l_lane = 0.f;                    // partial l for q row = r
  #pragma unroll
  for (int n = 0; n < 4; ++n) o_acc[n] = zf;

  stage(0, 0);
  int cur = 0;
  for (int kt = 0; kt < NS / KVBLK; ++kt) {
    __syncthreads();                          // this buffer's loads drained
    if (kt + 1 < NS / KVBLK) stage(cur ^ 1, kt + 1);
    const char* Kc = (const char*)&K_lds[cur][0];
    const char* Vc = (const char*)&Vt_lds[cur][0];

    #pragma unroll
    for (int h = 0; h < 2; ++h) {        // two 64-kv halves (R14 body each)
      // S^T = K Q^T : lane(g,r) gets S[kv = h*64 + jb*16+g*4+reg][q=r]
      f32x4 s[4];
      #pragma unroll
      for (int jb = 0; jb < 4; ++jb) {
        short8 bk[2];
        #pragma unroll
        for (int kk = 0; kk < 2; ++kk)
          bk[kk] = *reinterpret_cast<const short8*>(
              Kc + (h * 64 + jb * 16 + r) * 128 + ((kk * 64 + g * 16) ^ rkey));
        s[jb] = zf;
        #pragma unroll
        for (int kk = 0; kk < 2; ++kk)
          s[jb] = __builtin_amdgcn_mfma_f32_16x16x32_bf16(bk[kk], aq[kk], s[jb], 0, 0, 0);
      }

      // p = 2^(s); row-sum into per-lane l; pack PV A-frags in-register:
      // ap[kl][j] = P[q=r][pi-pos (2h+kl)*32 + g*8 + j]
      short8 ap[2];
      {
        float p[4][4];
        #pragma unroll
        for (int jb = 0; jb < 4; ++jb)
          #pragma unroll
          for (int reg = 0; reg < 4; ++reg)
            p[jb][reg] = __builtin_amdgcn_exp2f(s[jb][reg]);
        float t0 = (p[0][0] + p[0][1]) + (p[0][2] + p[0][3]);
        float t1 = (p[1][0] + p[1][1]) + (p[1][2] + p[1][3]);
        float t2 = (p[2][0] + p[2][1]) + (p[2][2] + p[2][3]);
        float t3 = (p[3][0] + p[3][1]) + (p[3][2] + p[3][3]);
        l_lane += (t0 + t1) + (t2 + t3);
        #pragma unroll
        for (int kl = 0; kl < 2; ++kl) {
          u32x4 w;
          w.x = cvt_pk_bf16(p[2 * kl][0], p[2 * kl][1]);
          w.y = cvt_pk_bf16(p[2 * kl][2], p[2 * kl][3]);
          w.z = cvt_pk_bf16(p[2 * kl + 1][0], p[2 * kl + 1][1]);
          w.w = cvt_pk_bf16(p[2 * kl + 1][2], p[2 * kl + 1][3]);
          ap[kl] = __builtin_bit_cast(short8, w);
        }
      }

      // O += P V (pi order): B[k_pv][col=d] from Vt_lds rows n*16+r (256B)
      #pragma unroll
      for (int n = 0; n < 4; ++n) {
        short8 bv[2];
        #pragma unroll
        for (int kl = 0; kl < 2; ++kl)
          bv[kl] = *reinterpret_cast<const short8*>(
              Vc + (n * 16 + r) * 256 + (((2 * h + kl) * 64 + g * 16) ^ vkey));
        #pragma unroll
        for (int kl = 0; kl < 2; ++kl)
          o_acc[n] = __builtin_amdgcn_mfma_f32_16x16x32_bf16(ap[kl], bv[kl], o_acc[n], 0, 0, 0);
      }
    }
    cur ^= 1;
  }

  // epilogue: complete l (sum over the 4 g-lanes holding row r), then
  // redistribute to the O layout (lane(g,r) needs l for q rows g*4+reg)
  {
    float l = l_lane;
    l += __shfl_xor(l, 16);
    l += __shfl_xor(l, 32);                   // all lanes: full l[q=r]
    #pragma unroll
    for (int reg = 0; reg < 4; ++reg) {
      float inv = 1.f / __shfl(l, g * 4 + reg);
      int row = qrow0 + g * 4 + reg;
      #pragma unroll
      for (int n = 0; n < 4; ++n)
        Os[(size_t)row * HD + n * 16 + r] = f2bf(o_acc[n][reg] * inv);
    }
  }
}

extern "C" void kernel_launch(void* const* d_in, const int* in_sizes, int n_in,
                              void* d_out, int out_size, void* d_ws, size_t ws_size,
                              hipStream_t stream) {
  const float* x  = (const float*)d_in[0];
  const float* wq = (const float*)d_in[1];
  const float* bq = (const float*)d_in[2];
  const float* wu = (const float*)d_in[3];
  const float* bu = (const float*)d_in[4];
  float* out = (float*)d_out;

  char* ws = (char*)d_ws;
  unsigned short* xb  = (unsigned short*)(ws);                 // 8 MB (reused as vtb)
  unsigned short* qb  = (unsigned short*)(ws + (8u  << 20));   // 8 MB
  unsigned short* ob  = (unsigned short*)(ws + (16u << 20));   // 8 MB (qsb then O)
  unsigned short* wqb = (unsigned short*)(ws + (24u << 20));   // 2 MB
  unsigned short* wub = (unsigned short*)(ws + (26u << 20));   // 2 MB

  // all three f32->bf16 conversions in one launch
  const int nx = NTOK * EMB, nw = EMB * EMB;
  cvt_bf16x3_kernel<<<((nx + 2 * nw) / 8 + 255) / 256, 256, 0, stream>>>(
      x, xb, nx, wq, wqb, nw, wu, wub, nw);

  // q = x @ wq^T + bq -> qb (bf16) and qsb = bf16(q * SEXP2) (single-rounded)
  unsigned short* qsb = ob;   // alias: each attn block reads only its own
                              // q-rows, then writes exactly those rows as O
  gemm_bt_kernel<true><<<dim3(EMB / 64, NTOK / 64), 128, 0, stream>>>(
      xb, wqb, bq, qb, qsb, NTOK, EMB, EMB);

  // xb is dead now; reuse as vtb: per-slab pi-permuted transpose of qb
  unsigned short* vtb = xb;
  transpose_kernel<<<dim3(NS / 64, HEADS * NB), 256, 0, stream>>>(qb, vtb);

  // 512 blocks (16 qtiles x 32 slabs) x 512 threads; XCD swizzle in-kernel
  attn_kernel<<<dim3(512), 512, 0, stream>>>(qb, qsb, vtb, ob);

  // y = O @ wu^T + bu -> f32
  gemm_bt_kernel<false><<<dim3(EMB / 64, NTOK / 64), 128, 0, stream>>>(
      ob, wub, bu, out, (unsigned short*)nullptr, NTOK, EMB, EMB);
}

// Round 16
// 93.067 us; speedup vs baseline: 1.1160x; 1.1160x over previous
//
#include <hip/hip_runtime.h>
#include <stdint.h>

#define EMB 1024
#define HEADS 16
#define NB 2
#define NS 2048
#define HD 64
#define NTOK (NB*NS)          // 4096
#define KVBLK 64
#define QW 16                 // q rows per wave
#define SEXP2 0.04508421676368185f   // log2(e)/32, folded into prescaled Q

typedef __attribute__((ext_vector_type(8))) short short8;
typedef __attribute__((ext_vector_type(4))) float f32x4;
typedef __attribute__((ext_vector_type(4))) unsigned int u32x4;

// round-to-nearest-even f32 -> bf16 bits (epilogues / cvt only)
__device__ inline unsigned short f2bf(float f) {
  unsigned int x = __builtin_bit_cast(unsigned int, f);
  x += 0x7FFFu + ((x >> 16) & 1u);
  return (unsigned short)(x >> 16);
}

// HW packed f32x2 -> bf16x2 (RNE); no builtin on gfx950 (T12 recipe)
__device__ inline unsigned cvt_pk_bf16(float lo, float hi) {
  unsigned d;
  asm("v_cvt_pk_bf16_f32 %0, %1, %2" : "=v"(d) : "v"(lo), "v"(hi));
  return d;
}

// async global->LDS, 16B per lane; lds dest = wave-uniform base + lane*16
__device__ inline void gld16(const void* g, void* l) {
  __builtin_amdgcn_global_load_lds(
      (const __attribute__((address_space(1))) unsigned int*)g,
      (__attribute__((address_space(3))) unsigned int*)l, 16, 0, 0);
}

// x, wq, wu conversions in ONE launch (3-way range branch)
__global__ void cvt_bf16x3_kernel(const float* __restrict__ s0,
                                  unsigned short* __restrict__ d0, int n0,
                                  const float* __restrict__ s1,
                                  unsigned short* __restrict__ d1, int n1,
                                  const float* __restrict__ s2,
                                  unsigned short* __restrict__ d2, int n2) {
  int i = (blockIdx.x * blockDim.x + threadIdx.x) * 8;
  const float* s; unsigned short* d;
  if (i < n0) { s = s0 + i; d = d0 + i; }
  else if (i - n0 < n1) { s = s1 + (i - n0); d = d1 + (i - n0); }
  else if (i - n0 - n1 < n2) { s = s2 + (i - n0 - n1); d = d2 + (i - n0 - n1); }
  else return;
  float4 v0 = *reinterpret_cast<const float4*>(s);
  float4 v1 = *reinterpret_cast<const float4*>(s + 4);
  short8 o;
  o[0] = (short)f2bf(v0.x); o[1] = (short)f2bf(v0.y);
  o[2] = (short)f2bf(v0.z); o[3] = (short)f2bf(v0.w);
  o[4] = (short)f2bf(v1.x); o[5] = (short)f2bf(v1.y);
  o[6] = (short)f2bf(v1.z); o[7] = (short)f2bf(v1.w);
  *reinterpret_cast<short8*>(d) = o;
}

// per-slab transpose: src [32][2048][64] -> dst [32][64][2048], with the
// kv index PERMUTED within each 64-tile by invpi (matches in-register P
// packing of the swapped-QK^T path):
//   pv position p = kk*32 + g*8 + j  holds  kv = kk*32 + (j>>2)*16 + g*4 + (j&3)
//   invpi(p) = (p&32) | (((p>>2)&1)<<4) | (((p>>3)&3)<<2) | (p&3)
__global__ __launch_bounds__(256) void transpose_kernel(
    const unsigned short* __restrict__ src, unsigned short* __restrict__ dst) {
  __shared__ unsigned short t[64][72];   // pad: row stride 144B
  const int slab = blockIdx.y, kt = blockIdx.x;
  const unsigned short* s = src + ((size_t)slab * NS + kt * 64) * HD;
  unsigned short* d = dst + (size_t)slab * HD * NS + kt * 64;
  const int tid = threadIdx.x;
  #pragma unroll
  for (int c = 0; c < 2; ++c) {
    int idx = c * 256 + tid;             // 0..511
    int row = idx >> 3, col = (idx & 7) * 8;
    short8 v = *reinterpret_cast<const short8*>(s + row * HD + col);
    *reinterpret_cast<short8*>(&t[row][col]) = v;
  }
  __syncthreads();
  #pragma unroll
  for (int c = 0; c < 2; ++c) {
    int idx = c * 256 + tid;
    int drow = idx >> 3, col = (idx & 7) * 8;
    short8 v;
    #pragma unroll
    for (int j = 0; j < 8; ++j) {
      int p = col + j;
      int kv = (p & 32) | (((p >> 2) & 1) << 4) | (((p >> 3) & 3) << 2) | (p & 3);
      v[j] = t[kv][drow];
    }
    *reinterpret_cast<short8*>(d + (size_t)drow * NS + col) = v;
  }
}

// C[M][N] = A[M][K] * Bw[N][K]^T + bias[N].  BM=64 BN=64 BK=64, 128 threads
// (2 waves, each 32x64 out -> af reused over 4 n-frags: 12 reads : 16 MFMAs).
// Grid 1024 = 4 resident blocks/CU. dbuf, global_load_lds staging
// (linear dest + inverse-swizzled source), 2-phase.
// Optional second output: Qscaled = bf16((C)*SEXP2), single-rounded.
template<bool OUT_BF16>
__global__ __launch_bounds__(128) void gemm_bt_kernel(
    const unsigned short* __restrict__ A,
    const unsigned short* __restrict__ Bw,
    const float* __restrict__ bias,
    void* __restrict__ Cout,
    unsigned short* __restrict__ Qscaled,
    int M, int N, int K) {
  __shared__ __align__(16) unsigned short As[2][64 * 64];
  __shared__ __align__(16) unsigned short Bs[2][64 * 64];
  const int tid = threadIdx.x;
  const int lane = tid & 63;
  const int wave = tid >> 6;             // 0/1
  const int g = lane >> 4, r = lane & 15;
  const int brow = blockIdx.y * 64;
  const int bcol = blockIdx.x * 64;

  const f32x4 zf = {0.f, 0.f, 0.f, 0.f};
  f32x4 acc[2][4];
  #pragma unroll
  for (int m = 0; m < 2; ++m)
    #pragma unroll
    for (int n = 0; n < 4; ++n) acc[m][n] = zf;

  auto stage = [&](int bb, int k0) {
    #pragma unroll
    for (int i = 0; i < 4; ++i) {            // A: 64x64 = 8KB = 4 issues/wave
      int base = (wave * 4 + i) * 1024;
      int L = base + lane * 16;
      int row = L >> 7, lsl = ((L >> 4) & 7) ^ (row & 7);
      gld16((const char*)A + ((size_t)(brow + row) * K + k0) * 2 + lsl * 16,
            (char*)&As[bb][0] + base);
    }
    #pragma unroll
    for (int i = 0; i < 4; ++i) {            // B: 64x64 = 8KB = 4 issues/wave
      int base = (wave * 4 + i) * 1024;
      int L = base + lane * 16;
      int row = L >> 7, lsl = ((L >> 4) & 7) ^ (row & 7);
      gld16((const char*)Bw + ((size_t)(bcol + row) * K + k0) * 2 + lsl * 16,
            (char*)&Bs[bb][0] + base);
    }
  };

  stage(0, 0);
  int cur = 0;
  for (int k0 = 0; k0 < K; k0 += 64) {
    __syncthreads();                          // drains prev stage (vmcnt)
    if (k0 + 64 < K) stage(cur ^ 1, k0 + 64);
    const char* Ac = (const char*)&As[cur][0];
    const char* Bc = (const char*)&Bs[cur][0];
    short8 af[2][2], bfr[4][2];
    #pragma unroll
    for (int m = 0; m < 2; ++m) {
      int row = wave * 32 + m * 16 + r;
      #pragma unroll
      for (int kk = 0; kk < 2; ++kk)
        af[m][kk] = *reinterpret_cast<const short8*>(
            Ac + row * 128 + ((kk * 64 + g * 16) ^ ((row & 7) << 4)));
    }
    #pragma unroll
    for (int n = 0; n < 4; ++n) {
      int row = n * 16 + r;
      #pragma unroll
      for (int kk = 0; kk < 2; ++kk)
        bfr[n][kk] = *reinterpret_cast<const short8*>(
            Bc + row * 128 + ((kk * 64 + g * 16) ^ ((row & 7) << 4)));
    }
    #pragma unroll
    for (int kk = 0; kk < 2; ++kk)
      #pragma unroll
      for (int m = 0; m < 2; ++m)
        #pragma unroll
        for (int n = 0; n < 4; ++n)
          acc[m][n] = __builtin_amdgcn_mfma_f32_16x16x32_bf16(af[m][kk], bfr[n][kk], acc[m][n], 0, 0, 0);
    cur ^= 1;
  }

  #pragma unroll
  for (int n = 0; n < 4; ++n) {
    int col = bcol + n * 16 + r;
    float bv = bias[col];
    #pragma unroll
    for (int m = 0; m < 2; ++m) {
      #pragma unroll
      for (int reg = 0; reg < 4; ++reg) {
        int row = brow + wave * 32 + m * 16 + g * 4 + reg;
        float v = acc[m][n][reg] + bv;
        if (OUT_BF16)
          ((unsigned short*)Cout)[(size_t)row * N + col] = f2bf(v);
        else
          ((float*)Cout)[(size_t)row * N + col] = v;
        if (Qscaled)
          Qscaled[(size_t)row * N + col] = f2bf(v * SEXP2);
      }
    }
  }
}

// Flash attention (R14-verified, verbatim: best measured 45.6us).
// Q=K=V = contiguous slab [NS][HD]; Vt pre-transposed and pi-permuted.
// 8 waves x 16 q-rows (128 q-rows/block); KVBLK=64; no-max softmax
// (prescaled Q); SWAPPED QK^T so P packs in-register for PV.
// Grid: 1-D 512 (16 qtiles x 32 slabs), slab-grouped XCD swizzle;
// 4 blocks/CU = 32 waves/CU (hardware max).
__global__ __launch_bounds__(512) void attn_kernel(
    const unsigned short* __restrict__ qb,
    const unsigned short* __restrict__ qsb,
    const unsigned short* __restrict__ vtb,
    unsigned short* __restrict__ ob) {
  const int bid = blockIdx.x;            // 0..511
  const int xcd = bid & 7, idx = bid >> 3;   // idx 0..63
  const int slab = xcd * 4 + (idx >> 4);
  const int qtile = idx & 15;            // 128 q-rows per block
  const unsigned short* Qs = qb + (size_t)slab * NS * HD;
  const unsigned short* Qss = qsb + (size_t)slab * NS * HD;  // prescaled
  const unsigned short* Vts = vtb + (size_t)slab * HD * NS;  // [64][2048] pi-perm
  unsigned short* Os = ob + (size_t)slab * NS * HD;
  const int tid = threadIdx.x;
  const int lane = tid & 63;
  const int wave = tid >> 6;             // 0..7
  const int g = lane >> 4, r = lane & 15;
  const int qrow0 = qtile * 128 + wave * QW;
  const int rkey = (r & 7) << 4;

  __shared__ __align__(16) unsigned short K_lds[2][KVBLK * HD];   // [kv][64] swz
  __shared__ __align__(16) unsigned short Vt_lds[2][HD * KVBLK];  // [d][pi-kv] swz

  // 8 waves cover each 8KB tile with exactly 1 gld16 per wave per tensor
  auto stage = [&](int bb, int kt) {
    const char* Kg = (const char*)(Qs + (size_t)kt * KVBLK * HD);  // 8KB tile
    const char* Vg = (const char*)Vts + (size_t)kt * 128;          // col offset
    int base = wave * 1024;
    int L = base + lane * 16;
    int row = L >> 7, lsl = ((L >> 4) & 7) ^ (row & 7);
    gld16(Kg + row * 128 + lsl * 16, (char*)&K_lds[bb][0] + base);
    gld16(Vg + (size_t)row * (NS * 2) + lsl * 16, (char*)&Vt_lds[bb][0] + base);
  };

  // Q fragments from the prescaled buffer; B operand of swapped QK^T:
  // col q = r, k d = kk*32 + g*8..+7
  short8 aq[2];
  #pragma unroll
  for (int kk = 0; kk < 2; ++kk)
    aq[kk] = *reinterpret_cast<const short8*>(
        &Qss[(size_t)(qrow0 + r) * HD + kk * 32 + g * 8]);

  const f32x4 zf = {0.f, 0.f, 0.f, 0.f};
  f32x4 o_acc[4];
  float l_lane = 0.f;                    // partial l for q row = r
  #pragma unroll
  for (int n = 0; n < 4; ++n) o_acc[n] = zf;

  stage(0, 0);
  int cur = 0;
  for (int kt = 0; kt < NS / KVBLK; ++kt) {
    __syncthreads();                          // this buffer's loads drained
    if (kt + 1 < NS / KVBLK) stage(cur ^ 1, kt + 1);
    const char* Kc = (const char*)&K_lds[cur][0];
    const char* Vc = (const char*)&Vt_lds[cur][0];

    // S^T = K Q^T : lane(g,r) gets S[kv=jb*16+g*4+reg][q=r]
    f32x4 s[4];
    #pragma unroll
    for (int jb = 0; jb < 4; ++jb) {
      short8 bk[2];
      #pragma unroll
      for (int kk = 0; kk < 2; ++kk)
        bk[kk] = *reinterpret_cast<const short8*>(
            Kc + (jb * 16 + r) * 128 + ((kk * 64 + g * 16) ^ rkey));
      s[jb] = zf;
      #pragma unroll
      for (int kk = 0; kk < 2; ++kk)
        s[jb] = __builtin_amdgcn_mfma_f32_16x16x32_bf16(bk[kk], aq[kk], s[jb], 0, 0, 0);
    }

    // p = 2^(s); row-sum into per-lane l; pack PV A-frags in-register:
    // ap[kk][j] = P[q=r][kv = kk*32 + (j>>2)*16 + g*4 + (j&3)]
    short8 ap[2];
    {
      float p[4][4];
      #pragma unroll
      for (int jb = 0; jb < 4; ++jb)
        #pragma unroll
        for (int reg = 0; reg < 4; ++reg)
          p[jb][reg] = __builtin_amdgcn_exp2f(s[jb][reg]);
      float t0 = (p[0][0] + p[0][1]) + (p[0][2] + p[0][3]);
      float t1 = (p[1][0] + p[1][1]) + (p[1][2] + p[1][3]);
      float t2 = (p[2][0] + p[2][1]) + (p[2][2] + p[2][3]);
      float t3 = (p[3][0] + p[3][1]) + (p[3][2] + p[3][3]);
      l_lane += (t0 + t1) + (t2 + t3);
      #pragma unroll
      for (int kk = 0; kk < 2; ++kk) {
        u32x4 w;
        w.x = cvt_pk_bf16(p[2 * kk][0], p[2 * kk][1]);
        w.y = cvt_pk_bf16(p[2 * kk][2], p[2 * kk][3]);
        w.z = cvt_pk_bf16(p[2 * kk + 1][0], p[2 * kk + 1][1]);
        w.w = cvt_pk_bf16(p[2 * kk + 1][2], p[2 * kk + 1][3]);
        ap[kk] = __builtin_bit_cast(short8, w);
      }
    }

    // O += P V (pi order): B[k_pv][col=d] from Vt_lds rows n*16+r
    #pragma unroll
    for (int n = 0; n < 4; ++n) {
      short8 bv[2];
      #pragma unroll
      for (int kk = 0; kk < 2; ++kk)
        bv[kk] = *reinterpret_cast<const short8*>(
            Vc + (n * 16 + r) * 128 + ((kk * 64 + g * 16) ^ rkey));
      #pragma unroll
      for (int kk = 0; kk < 2; ++kk)
        o_acc[n] = __builtin_amdgcn_mfma_f32_16x16x32_bf16(ap[kk], bv[kk], o_acc[n], 0, 0, 0);
    }
    cur ^= 1;
  }

  // epilogue: complete l (sum over the 4 g-lanes holding row r), then
  // redistribute to the O layout (lane(g,r) needs l for q rows g*4+reg)
  {
    float l = l_lane;
    l += __shfl_xor(l, 16);
    l += __shfl_xor(l, 32);                   // all lanes: full l[q=r]
    #pragma unroll
    for (int reg = 0; reg < 4; ++reg) {
      float inv = 1.f / __shfl(l, g * 4 + reg);
      int row = qrow0 + g * 4 + reg;
      #pragma unroll
      for (int n = 0; n < 4; ++n)
        Os[(size_t)row * HD + n * 16 + r] = f2bf(o_acc[n][reg] * inv);
    }
  }
}

extern "C" void kernel_launch(void* const* d_in, const int* in_sizes, int n_in,
                              void* d_out, int out_size, void* d_ws, size_t ws_size,
                              hipStream_t stream) {
  const float* x  = (const float*)d_in[0];
  const float* wq = (const float*)d_in[1];
  const float* bq = (const float*)d_in[2];
  const float* wu = (const float*)d_in[3];
  const float* bu = (const float*)d_in[4];
  float* out = (float*)d_out;

  char* ws = (char*)d_ws;
  unsigned short* xb  = (unsigned short*)(ws);                 // 8 MB (reused as vtb)
  unsigned short* qb  = (unsigned short*)(ws + (8u  << 20));   // 8 MB
  unsigned short* ob  = (unsigned short*)(ws + (16u << 20));   // 8 MB (qsb then O)
  unsigned short* wqb = (unsigned short*)(ws + (24u << 20));   // 2 MB
  unsigned short* wub = (unsigned short*)(ws + (26u << 20));   // 2 MB

  // all three f32->bf16 conversions in one launch
  const int nx = NTOK * EMB, nw = EMB * EMB;
  cvt_bf16x3_kernel<<<((nx + 2 * nw) / 8 + 255) / 256, 256, 0, stream>>>(
      x, xb, nx, wq, wqb, nw, wu, wub, nw);

  // q = x @ wq^T + bq -> qb (bf16) and qsb = bf16(q * SEXP2) (single-rounded)
  unsigned short* qsb = ob;   // alias: each attn block reads only its own
                              // q-rows, then writes exactly those rows as O
  gemm_bt_kernel<true><<<dim3(EMB / 64, NTOK / 64), 128, 0, stream>>>(
      xb, wqb, bq, qb, qsb, NTOK, EMB, EMB);

  // xb is dead now; reuse as vtb: per-slab pi-permuted transpose of qb
  unsigned short* vtb = xb;
  transpose_kernel<<<dim3(NS / 64, HEADS * NB), 256, 0, stream>>>(qb, vtb);

  // 512 blocks (16 qtiles x 32 slabs) x 512 threads; XCD swizzle in-kernel
  attn_kernel<<<dim3(512), 512, 0, stream>>>(qb, qsb, vtb, ob);

  // y = O @ wu^T + bu -> f32
  gemm_bt_kernel<false><<<dim3(EMB / 64, NTOK / 64), 128, 0, stream>>>(
      ob, wub, bu, out, (unsigned short*)nullptr, NTOK, EMB, EMB);
}

// Round 17
// 91.260 us; speedup vs baseline: 1.1381x; 1.0198x over previous
//
#include <hip/hip_runtime.h>
#include <stdint.h>

#define EMB 1024
#define HEADS 16
#define NB 2
#define NS 2048
#define HD 64
#define NTOK (NB*NS)          // 4096
#define KVBLK 64
#define SEXP2 0.04508421676368185f   // log2(e)/32, folded into prescaled Q

typedef __attribute__((ext_vector_type(8))) short short8;
typedef __attribute__((ext_vector_type(4))) float f32x4;
typedef __attribute__((ext_vector_type(4))) unsigned int u32x4;

// round-to-nearest-even f32 -> bf16 bits (epilogues / cvt only)
__device__ inline unsigned short f2bf(float f) {
  unsigned int x = __builtin_bit_cast(unsigned int, f);
  x += 0x7FFFu + ((x >> 16) & 1u);
  return (unsigned short)(x >> 16);
}

// HW packed f32x2 -> bf16x2 (RNE); no builtin on gfx950 (T12 recipe)
__device__ inline unsigned cvt_pk_bf16(float lo, float hi) {
  unsigned d;
  asm("v_cvt_pk_bf16_f32 %0, %1, %2" : "=v"(d) : "v"(lo), "v"(hi));
  return d;
}

// async global->LDS, 16B per lane; lds dest = wave-uniform base + lane*16
__device__ inline void gld16(const void* g, void* l) {
  __builtin_amdgcn_global_load_lds(
      (const __attribute__((address_space(1))) unsigned int*)g,
      (__attribute__((address_space(3))) unsigned int*)l, 16, 0, 0);
}

// x, wq, wu conversions in ONE launch (3-way range branch)
__global__ void cvt_bf16x3_kernel(const float* __restrict__ s0,
                                  unsigned short* __restrict__ d0, int n0,
                                  const float* __restrict__ s1,
                                  unsigned short* __restrict__ d1, int n1,
                                  const float* __restrict__ s2,
                                  unsigned short* __restrict__ d2, int n2) {
  int i = (blockIdx.x * blockDim.x + threadIdx.x) * 8;
  const float* s; unsigned short* d;
  if (i < n0) { s = s0 + i; d = d0 + i; }
  else if (i - n0 < n1) { s = s1 + (i - n0); d = d1 + (i - n0); }
  else if (i - n0 - n1 < n2) { s = s2 + (i - n0 - n1); d = d2 + (i - n0 - n1); }
  else return;
  float4 v0 = *reinterpret_cast<const float4*>(s);
  float4 v1 = *reinterpret_cast<const float4*>(s + 4);
  short8 o;
  o[0] = (short)f2bf(v0.x); o[1] = (short)f2bf(v0.y);
  o[2] = (short)f2bf(v0.z); o[3] = (short)f2bf(v0.w);
  o[4] = (short)f2bf(v1.x); o[5] = (short)f2bf(v1.y);
  o[6] = (short)f2bf(v1.z); o[7] = (short)f2bf(v1.w);
  *reinterpret_cast<short8*>(d) = o;
}

// per-slab transpose: src [32][2048][64] -> dst [32][64][2048], with the
// kv index PERMUTED within each 64-tile by invpi (matches in-register P
// packing of the swapped-QK^T path):
//   pv position p = kk*32 + g*8 + j  holds  kv = kk*32 + (j>>2)*16 + g*4 + (j&3)
//   invpi(p) = (p&32) | (((p>>2)&1)<<4) | (((p>>3)&3)<<2) | (p&3)
__global__ __launch_bounds__(256) void transpose_kernel(
    const unsigned short* __restrict__ src, unsigned short* __restrict__ dst) {
  __shared__ unsigned short t[64][72];   // pad: row stride 144B
  const int slab = blockIdx.y, kt = blockIdx.x;
  const unsigned short* s = src + ((size_t)slab * NS + kt * 64) * HD;
  unsigned short* d = dst + (size_t)slab * HD * NS + kt * 64;
  const int tid = threadIdx.x;
  #pragma unroll
  for (int c = 0; c < 2; ++c) {
    int idx = c * 256 + tid;             // 0..511
    int row = idx >> 3, col = (idx & 7) * 8;
    short8 v = *reinterpret_cast<const short8*>(s + row * HD + col);
    *reinterpret_cast<short8*>(&t[row][col]) = v;
  }
  __syncthreads();
  #pragma unroll
  for (int c = 0; c < 2; ++c) {
    int idx = c * 256 + tid;
    int drow = idx >> 3, col = (idx & 7) * 8;
    short8 v;
    #pragma unroll
    for (int j = 0; j < 8; ++j) {
      int p = col + j;
      int kv = (p & 32) | (((p >> 2) & 1) << 4) | (((p >> 3) & 3) << 2) | (p & 3);
      v[j] = t[kv][drow];
    }
    *reinterpret_cast<short8*>(d + (size_t)drow * NS + col) = v;
  }
}

// C[M][N] = A[M][K] * Bw[N][K]^T + bias[N].  BM=64 BN=64 BK=64 (R12/R14-
// proven: 1024 blocks = 4/CU, 16 waves/CU), dbuf, global_load_lds staging
// (linear dest + inverse-swizzled source), 2-phase. 4 waves (2x2), 32x32 out.
// Optional second output: Qscaled = bf16((C)*SEXP2), single-rounded.
template<bool OUT_BF16>
__global__ __launch_bounds__(256) void gemm_bt_kernel(
    const unsigned short* __restrict__ A,
    const unsigned short* __restrict__ Bw,
    const float* __restrict__ bias,
    void* __restrict__ Cout,
    unsigned short* __restrict__ Qscaled,
    int M, int N, int K) {
  __shared__ __align__(16) unsigned short As[2][64 * 64];
  __shared__ __align__(16) unsigned short Bs[2][64 * 64];
  const int tid = threadIdx.x;
  const int lane = tid & 63;
  const int wave = tid >> 6;
  const int wr = wave >> 1, wc = wave & 1;
  const int g = lane >> 4, r = lane & 15;
  const int brow = blockIdx.y * 64;
  const int bcol = blockIdx.x * 64;

  const f32x4 zf = {0.f, 0.f, 0.f, 0.f};
  f32x4 acc[2][2];
  #pragma unroll
  for (int m = 0; m < 2; ++m)
    #pragma unroll
    for (int n = 0; n < 2; ++n) acc[m][n] = zf;

  auto stage = [&](int bb, int k0) {
    #pragma unroll
    for (int i = 0; i < 2; ++i) {            // A: 64x64 = 8KB = 2 issues
      int base = i * 4096 + wave * 1024;
      int L = base + lane * 16;
      int row = L >> 7, lsl = ((L >> 4) & 7) ^ (row & 7);
      gld16((const char*)A + ((size_t)(brow + row) * K + k0) * 2 + lsl * 16,
            (char*)&As[bb][0] + base);
    }
    #pragma unroll
    for (int i = 0; i < 2; ++i) {            // B: 64x64 = 8KB = 2 issues
      int base = i * 4096 + wave * 1024;
      int L = base + lane * 16;
      int row = L >> 7, lsl = ((L >> 4) & 7) ^ (row & 7);
      gld16((const char*)Bw + ((size_t)(bcol + row) * K + k0) * 2 + lsl * 16,
            (char*)&Bs[bb][0] + base);
    }
  };

  stage(0, 0);
  int cur = 0;
  for (int k0 = 0; k0 < K; k0 += 64) {
    __syncthreads();                          // drains prev stage (vmcnt)
    if (k0 + 64 < K) stage(cur ^ 1, k0 + 64);
    const char* Ac = (const char*)&As[cur][0];
    const char* Bc = (const char*)&Bs[cur][0];
    short8 af[2][2], bfr[2][2];
    #pragma unroll
    for (int m = 0; m < 2; ++m) {
      int row = wr * 32 + m * 16 + r;
      #pragma unroll
      for (int kk = 0; kk < 2; ++kk)
        af[m][kk] = *reinterpret_cast<const short8*>(
            Ac + row * 128 + ((kk * 64 + g * 16) ^ ((row & 7) << 4)));
    }
    #pragma unroll
    for (int n = 0; n < 2; ++n) {
      int row = wc * 32 + n * 16 + r;
      #pragma unroll
      for (int kk = 0; kk < 2; ++kk)
        bfr[n][kk] = *reinterpret_cast<const short8*>(
            Bc + row * 128 + ((kk * 64 + g * 16) ^ ((row & 7) << 4)));
    }
    #pragma unroll
    for (int kk = 0; kk < 2; ++kk)
      #pragma unroll
      for (int m = 0; m < 2; ++m)
        #pragma unroll
        for (int n = 0; n < 2; ++n)
          acc[m][n] = __builtin_amdgcn_mfma_f32_16x16x32_bf16(af[m][kk], bfr[n][kk], acc[m][n], 0, 0, 0);
    cur ^= 1;
  }

  #pragma unroll
  for (int n = 0; n < 2; ++n) {
    int col = bcol + wc * 32 + n * 16 + r;
    float bv = bias[col];
    #pragma unroll
    for (int m = 0; m < 2; ++m) {
      #pragma unroll
      for (int reg = 0; reg < 4; ++reg) {
        int row = brow + wr * 32 + m * 16 + g * 4 + reg;
        float v = acc[m][n][reg] + bv;
        if (OUT_BF16)
          ((unsigned short*)Cout)[(size_t)row * N + col] = f2bf(v);
        else
          ((float*)Cout)[(size_t)row * N + col] = v;
        if (Qscaled)
          Qscaled[(size_t)row * N + col] = f2bf(v * SEXP2);
      }
    }
  }
}

// Flash attention, QW=32 with EXACT kv-split x2 (no-max softmax = order-free
// kv sum). Block = 8 waves = 4 q-subtiles(32 rows) x 2 kv-streams; stream h
// owns kv tiles {2t+h}. Per stream: R14's K/V LDS layouts + staging math
// (kt -> 2t+h only); compute body = R7's verified QW=32 body verbatim.
// Epilogue: h=1 writes O/l partials to dead staging LDS; h=0 adds and runs
// R7's normalize/write. Grid 512 (16 qtiles x 32 slabs), XCD swizzle;
// LDS 64KB -> 2 blocks/CU = 16 waves/CU.
__global__ __launch_bounds__(512) void attn_kernel(
    const unsigned short* __restrict__ qb,
    const unsigned short* __restrict__ qsb,
    const unsigned short* __restrict__ vtb,
    unsigned short* __restrict__ ob) {
  const int bid = blockIdx.x;            // 0..511
  const int xcd = bid & 7, idx = bid >> 3;   // idx 0..63
  const int slab = xcd * 4 + (idx >> 4);
  const int qtile = idx & 15;            // 128 q-rows per block
  const unsigned short* Qs = qb + (size_t)slab * NS * HD;
  const unsigned short* Qss = qsb + (size_t)slab * NS * HD;  // prescaled
  const unsigned short* Vts = vtb + (size_t)slab * HD * NS;  // [64][2048] pi-perm
  unsigned short* Os = ob + (size_t)slab * NS * HD;
  const int tid = threadIdx.x;
  const int lane = tid & 63;
  const int wave = tid >> 6;             // 0..7
  const int qsub = wave >> 1;            // 0..3: which 32 q-rows
  const int h = wave & 1;                // 0/1: kv stream
  const int g = lane >> 4, r = lane & 15;
  const int qrow0 = qtile * 128 + qsub * 32;
  const int rkey = (r & 7) << 4;

  __shared__ __align__(16) unsigned short K_lds[2][2][KVBLK * HD];   // [h][buf]
  __shared__ __align__(16) unsigned short Vt_lds[2][2][HD * KVBLK];  // [h][buf]

  // stream h's tile t = global kv tile 2t+h; staged by the 4 waves of
  // stream h (2 gld16 per tensor per wave). Address math = R14 verbatim.
  auto stage = [&](int bb, int t) {
    int kt2 = 2 * t + h;
    const char* Kg = (const char*)Qs + (size_t)kt2 * 8192;   // 8KB K tile
    const char* Vg = (const char*)Vts + (size_t)kt2 * 128;   // col offset
    #pragma unroll
    for (int i = 0; i < 2; ++i) {
      int base = (qsub * 2 + i) * 1024;
      int L = base + lane * 16;
      int row = L >> 7, lsl = ((L >> 4) & 7) ^ (row & 7);
      gld16(Kg + row * 128 + lsl * 16, (char*)&K_lds[h][bb][0] + base);
      gld16(Vg + (size_t)row * (NS * 2) + lsl * 16, (char*)&Vt_lds[h][bb][0] + base);
    }
  };

  // Q fragments (prescaled): B operand of swapped QK^T:
  // col q = qrow0 + m*16 + r, k d = kk*32 + g*8..+7   (R7 verbatim)
  short8 aq[2][2];
  #pragma unroll
  for (int m = 0; m < 2; ++m)
    #pragma unroll
    for (int kk = 0; kk < 2; ++kk)
      aq[m][kk] = *reinterpret_cast<const short8*>(
          &Qss[(size_t)(qrow0 + m * 16 + r) * HD + kk * 32 + g * 8]);

  const f32x4 zf = {0.f, 0.f, 0.f, 0.f};
  f32x4 o_acc[2][4];
  float l_lane[2] = {0.f, 0.f};          // partial l for q = m*16 + r
  #pragma unroll
  for (int m = 0; m < 2; ++m)
    #pragma unroll
    for (int n = 0; n < 4; ++n) o_acc[m][n] = zf;

  stage(0, 0);
  int cur = 0;
  for (int t = 0; t < NS / KVBLK / 2; ++t) {   // 16 iters per stream
    __syncthreads();                          // staged tiles visible
    if (t + 1 < NS / KVBLK / 2) stage(cur ^ 1, t + 1);
    const char* Kc = (const char*)&K_lds[h][cur][0];
    const char* Vc = (const char*)&Vt_lds[h][cur][0];

    // S^T = K Q^T : lane(g,r) gets S[kv=jb*16+g*4+reg][q=m*16+r]
    f32x4 s[2][4];
    #pragma unroll
    for (int jb = 0; jb < 4; ++jb) {
      short8 bk[2];
      #pragma unroll
      for (int kk = 0; kk < 2; ++kk)
        bk[kk] = *reinterpret_cast<const short8*>(
            Kc + (jb * 16 + r) * 128 + ((kk * 64 + g * 16) ^ rkey));
      #pragma unroll
      for (int m = 0; m < 2; ++m) {
        s[m][jb] = zf;
        #pragma unroll
        for (int kk = 0; kk < 2; ++kk)
          s[m][jb] = __builtin_amdgcn_mfma_f32_16x16x32_bf16(bk[kk], aq[m][kk], s[m][jb], 0, 0, 0);
      }
    }

    // p = 2^(s); row-sum into per-lane l; pack PV A-frags in-register:
    // ap[m][kk][j] = P[q=m*16+r][kv = kk*32 + (j>>2)*16 + g*4 + (j&3)]
    short8 ap[2][2];
    #pragma unroll
    for (int m = 0; m < 2; ++m) {
      float p[4][4];
      #pragma unroll
      for (int jb = 0; jb < 4; ++jb)
        #pragma unroll
        for (int reg = 0; reg < 4; ++reg)
          p[jb][reg] = __builtin_amdgcn_exp2f(s[m][jb][reg]);
      float t0 = (p[0][0] + p[0][1]) + (p[0][2] + p[0][3]);
      float t1 = (p[1][0] + p[1][1]) + (p[1][2] + p[1][3]);
      float t2 = (p[2][0] + p[2][1]) + (p[2][2] + p[2][3]);
      float t3 = (p[3][0] + p[3][1]) + (p[3][2] + p[3][3]);
      l_lane[m] += (t0 + t1) + (t2 + t3);
      #pragma unroll
      for (int kk = 0; kk < 2; ++kk) {
        u32x4 w;
        w.x = cvt_pk_bf16(p[2 * kk][0], p[2 * kk][1]);
        w.y = cvt_pk_bf16(p[2 * kk][2], p[2 * kk][3]);
        w.z = cvt_pk_bf16(p[2 * kk + 1][0], p[2 * kk + 1][1]);
        w.w = cvt_pk_bf16(p[2 * kk + 1][2], p[2 * kk + 1][3]);
        ap[m][kk] = __builtin_bit_cast(short8, w);
      }
    }

    // O += P V (pi order): B[k_pv][col=d] from Vt_lds rows n*16+r
    #pragma unroll
    for (int n = 0; n < 4; ++n) {
      short8 bv[2];
      #pragma unroll
      for (int kk = 0; kk < 2; ++kk)
        bv[kk] = *reinterpret_cast<const short8*>(
            Vc + (n * 16 + r) * 128 + ((kk * 64 + g * 16) ^ rkey));
      #pragma unroll
      for (int m = 0; m < 2; ++m)
        #pragma unroll
        for (int kk = 0; kk < 2; ++kk)
          o_acc[m][n] = __builtin_amdgcn_mfma_f32_16x16x32_bf16(ap[m][kk], bv[kk], o_acc[m][n], 0, 0, 0);
    }
    cur ^= 1;
  }

  // cross-stream reduction through the (now dead) staging LDS.
  // Layout: O partials at K_lds base, qsub*8KB + (m*4+n)*1024 + lane*16
  // (lanes contiguous 16B -> conflict-free); l partials at Vt_lds base,
  // qsub*512 + lane*8.
  __syncthreads();                       // all staging/compute complete
  char* redO = (char*)&K_lds[0][0][0];
  char* redL = (char*)&Vt_lds[0][0][0];
  if (h == 1) {
    #pragma unroll
    for (int m = 0; m < 2; ++m)
      #pragma unroll
      for (int n = 0; n < 4; ++n)
        *reinterpret_cast<f32x4*>(redO + qsub * 8192 + (m * 4 + n) * 1024 + lane * 16) = o_acc[m][n];
    float2 lp; lp.x = l_lane[0]; lp.y = l_lane[1];
    *reinterpret_cast<float2*>(redL + qsub * 512 + lane * 8) = lp;
  }
  __syncthreads();
  if (h == 0) {
    #pragma unroll
    for (int m = 0; m < 2; ++m)
      #pragma unroll
      for (int n = 0; n < 4; ++n)
        o_acc[m][n] += *reinterpret_cast<f32x4*>(
            redO + qsub * 8192 + (m * 4 + n) * 1024 + lane * 16);
    float2 lp = *reinterpret_cast<float2*>(redL + qsub * 512 + lane * 8);
    l_lane[0] += lp.x; l_lane[1] += lp.y;

    // epilogue (R7 verbatim): complete l across g-lanes, normalize, write O
    #pragma unroll
    for (int m = 0; m < 2; ++m) {
      float l = l_lane[m];
      l += __shfl_xor(l, 16);
      l += __shfl_xor(l, 32);                 // all lanes: full l[q=m*16+r]
      #pragma unroll
      for (int reg = 0; reg < 4; ++reg) {
        float inv = 1.f / __shfl(l, g * 4 + reg);
        int row = qrow0 + m * 16 + g * 4 + reg;
        #pragma unroll
        for (int n = 0; n < 4; ++n)
          Os[(size_t)row * HD + n * 16 + r] = f2bf(o_acc[m][n][reg] * inv);
      }
    }
  }
}

extern "C" void kernel_launch(void* const* d_in, const int* in_sizes, int n_in,
                              void* d_out, int out_size, void* d_ws, size_t ws_size,
                              hipStream_t stream) {
  const float* x  = (const float*)d_in[0];
  const float* wq = (const float*)d_in[1];
  const float* bq = (const float*)d_in[2];
  const float* wu = (const float*)d_in[3];
  const float* bu = (const float*)d_in[4];
  float* out = (float*)d_out;

  char* ws = (char*)d_ws;
  unsigned short* xb  = (unsigned short*)(ws);                 // 8 MB (reused as vtb)
  unsigned short* qb  = (unsigned short*)(ws + (8u  << 20));   // 8 MB
  unsigned short* ob  = (unsigned short*)(ws + (16u << 20));   // 8 MB (qsb then O)
  unsigned short* wqb = (unsigned short*)(ws + (24u << 20));   // 2 MB
  unsigned short* wub = (unsigned short*)(ws + (26u << 20));   // 2 MB

  // all three f32->bf16 conversions in one launch
  const int nx = NTOK * EMB, nw = EMB * EMB;
  cvt_bf16x3_kernel<<<((nx + 2 * nw) / 8 + 255) / 256, 256, 0, stream>>>(
      x, xb, nx, wq, wqb, nw, wu, wub, nw);

  // q = x @ wq^T + bq -> qb (bf16) and qsb = bf16(q * SEXP2) (single-rounded)
  unsigned short* qsb = ob;   // alias: each attn block reads only its own
                              // q-rows, then writes exactly those rows as O
  gemm_bt_kernel<true><<<dim3(EMB / 64, NTOK / 64), 256, 0, stream>>>(
      xb, wqb, bq, qb, qsb, NTOK, EMB, EMB);

  // xb is dead now; reuse as vtb: per-slab pi-permuted transpose of qb
  unsigned short* vtb = xb;
  transpose_kernel<<<dim3(NS / 64, HEADS * NB), 256, 0, stream>>>(qb, vtb);

  // 512 blocks (16 qtiles x 32 slabs) x 512 threads; XCD swizzle in-kernel
  attn_kernel<<<dim3(512), 512, 0, stream>>>(qb, qsb, vtb, ob);

  // y = O @ wu^T + bu -> f32
  gemm_bt_kernel<false><<<dim3(EMB / 64, NTOK / 64), 256, 0, stream>>>(
      ob, wub, bu, out, (unsigned short*)nullptr, NTOK, EMB, EMB);
}

// Round 18
// 89.073 us; speedup vs baseline: 1.1660x; 1.0246x over previous
//
#include <hip/hip_runtime.h>
#include <stdint.h>
#include <math.h>

#define EMB 1024
#define HEADS 16
#define NB 2
#define NS 2048
#define HD 64
#define NTOK (NB*NS)          // 4096
#define KVBLK 64
#define SEXP2 0.04508421676368185f   // log2(e)/32; sqrt folded into qhb

typedef __attribute__((ext_vector_type(8))) short short8;
typedef __attribute__((ext_vector_type(4))) float f32x4;
typedef __attribute__((ext_vector_type(4))) unsigned int u32x4;

// round-to-nearest-even f32 -> bf16 bits (epilogues / cvt only)
__device__ inline unsigned short f2bf(float f) {
  unsigned int x = __builtin_bit_cast(unsigned int, f);
  x += 0x7FFFu + ((x >> 16) & 1u);
  return (unsigned short)(x >> 16);
}

// HW packed f32x2 -> bf16x2 (RNE); no builtin on gfx950 (T12 recipe)
__device__ inline unsigned cvt_pk_bf16(float lo, float hi) {
  unsigned d;
  asm("v_cvt_pk_bf16_f32 %0, %1, %2" : "=v"(d) : "v"(lo), "v"(hi));
  return d;
}

// async global->LDS, 16B per lane; lds dest = wave-uniform base + lane*16
__device__ inline void gld16(const void* g, void* l) {
  __builtin_amdgcn_global_load_lds(
      (const __attribute__((address_space(1))) unsigned int*)g,
      (__attribute__((address_space(3))) unsigned int*)l, 16, 0, 0);
}

// x, wq, wu conversions in ONE launch (3-way range branch)
__global__ void cvt_bf16x3_kernel(const float* __restrict__ s0,
                                  unsigned short* __restrict__ d0, int n0,
                                  const float* __restrict__ s1,
                                  unsigned short* __restrict__ d1, int n1,
                                  const float* __restrict__ s2,
                                  unsigned short* __restrict__ d2, int n2) {
  int i = (blockIdx.x * blockDim.x + threadIdx.x) * 8;
  const float* s; unsigned short* d;
  if (i < n0) { s = s0 + i; d = d0 + i; }
  else if (i - n0 < n1) { s = s1 + (i - n0); d = d1 + (i - n0); }
  else if (i - n0 - n1 < n2) { s = s2 + (i - n0 - n1); d = d2 + (i - n0 - n1); }
  else return;
  float4 v0 = *reinterpret_cast<const float4*>(s);
  float4 v1 = *reinterpret_cast<const float4*>(s + 4);
  short8 o;
  o[0] = (short)f2bf(v0.x); o[1] = (short)f2bf(v0.y);
  o[2] = (short)f2bf(v0.z); o[3] = (short)f2bf(v0.w);
  o[4] = (short)f2bf(v1.x); o[5] = (short)f2bf(v1.y);
  o[6] = (short)f2bf(v1.z); o[7] = (short)f2bf(v1.w);
  *reinterpret_cast<short8*>(d) = o;
}

// per-slab transpose: src [32][2048][64] -> dst [32][64][2048], with the
// kv index PERMUTED within each 64-tile by invpi (matches in-register P
// packing of the swapped-QK^T path):
//   pv position p = kk*32 + g*8 + j  holds  kv = kk*32 + (j>>2)*16 + g*4 + (j&3)
//   invpi(p) = (p&32) | (((p>>2)&1)<<4) | (((p>>3)&3)<<2) | (p&3)
__global__ __launch_bounds__(256) void transpose_kernel(
    const unsigned short* __restrict__ src, unsigned short* __restrict__ dst) {
  __shared__ unsigned short t[64][72];   // pad: row stride 144B
  const int slab = blockIdx.y, kt = blockIdx.x;
  const unsigned short* s = src + ((size_t)slab * NS + kt * 64) * HD;
  unsigned short* d = dst + (size_t)slab * HD * NS + kt * 64;
  const int tid = threadIdx.x;
  #pragma unroll
  for (int c = 0; c < 2; ++c) {
    int idx = c * 256 + tid;             // 0..511
    int row = idx >> 3, col = (idx & 7) * 8;
    short8 v = *reinterpret_cast<const short8*>(s + row * HD + col);
    *reinterpret_cast<short8*>(&t[row][col]) = v;
  }
  __syncthreads();
  #pragma unroll
  for (int c = 0; c < 2; ++c) {
    int idx = c * 256 + tid;
    int drow = idx >> 3, col = (idx & 7) * 8;
    short8 v;
    #pragma unroll
    for (int j = 0; j < 8; ++j) {
      int p = col + j;
      int kv = (p & 32) | (((p >> 2) & 1) << 4) | (((p >> 3) & 3) << 2) | (p & 3);
      v[j] = t[kv][drow];
    }
    *reinterpret_cast<short8*>(d + (size_t)drow * NS + col) = v;
  }
}

// C[M][N] = A[M][K] * Bw[N][K]^T + bias[N].  BM=64 BN=64 BK=64 (R12/R14-
// proven: 1024 blocks = 4/CU, 16 waves/CU), dbuf, global_load_lds staging
// (linear dest + inverse-swizzled source), 2-phase. 4 waves (2x2), 32x32 out.
// OUT_BF16 path writes f2bf(v * oscale) (oscale folded at compile site).
template<bool OUT_BF16>
__global__ __launch_bounds__(256) void gemm_bt_kernel(
    const unsigned short* __restrict__ A,
    const unsigned short* __restrict__ Bw,
    const float* __restrict__ bias,
    void* __restrict__ Cout,
    float oscale,
    int M, int N, int K) {
  __shared__ __align__(16) unsigned short As[2][64 * 64];
  __shared__ __align__(16) unsigned short Bs[2][64 * 64];
  const int tid = threadIdx.x;
  const int lane = tid & 63;
  const int wave = tid >> 6;
  const int wr = wave >> 1, wc = wave & 1;
  const int g = lane >> 4, r = lane & 15;
  const int brow = blockIdx.y * 64;
  const int bcol = blockIdx.x * 64;

  const f32x4 zf = {0.f, 0.f, 0.f, 0.f};
  f32x4 acc[2][2];
  #pragma unroll
  for (int m = 0; m < 2; ++m)
    #pragma unroll
    for (int n = 0; n < 2; ++n) acc[m][n] = zf;

  auto stage = [&](int bb, int k0) {
    #pragma unroll
    for (int i = 0; i < 2; ++i) {            // A: 64x64 = 8KB = 2 issues
      int base = i * 4096 + wave * 1024;
      int L = base + lane * 16;
      int row = L >> 7, lsl = ((L >> 4) & 7) ^ (row & 7);
      gld16((const char*)A + ((size_t)(brow + row) * K + k0) * 2 + lsl * 16,
            (char*)&As[bb][0] + base);
    }
    #pragma unroll
    for (int i = 0; i < 2; ++i) {            // B: 64x64 = 8KB = 2 issues
      int base = i * 4096 + wave * 1024;
      int L = base + lane * 16;
      int row = L >> 7, lsl = ((L >> 4) & 7) ^ (row & 7);
      gld16((const char*)Bw + ((size_t)(bcol + row) * K + k0) * 2 + lsl * 16,
            (char*)&Bs[bb][0] + base);
    }
  };

  stage(0, 0);
  int cur = 0;
  for (int k0 = 0; k0 < K; k0 += 64) {
    __syncthreads();                          // drains prev stage (vmcnt)
    if (k0 + 64 < K) stage(cur ^ 1, k0 + 64);
    const char* Ac = (const char*)&As[cur][0];
    const char* Bc = (const char*)&Bs[cur][0];
    short8 af[2][2], bfr[2][2];
    #pragma unroll
    for (int m = 0; m < 2; ++m) {
      int row = wr * 32 + m * 16 + r;
      #pragma unroll
      for (int kk = 0; kk < 2; ++kk)
        af[m][kk] = *reinterpret_cast<const short8*>(
            Ac + row * 128 + ((kk * 64 + g * 16) ^ ((row & 7) << 4)));
    }
    #pragma unroll
    for (int n = 0; n < 2; ++n) {
      int row = wc * 32 + n * 16 + r;
      #pragma unroll
      for (int kk = 0; kk < 2; ++kk)
        bfr[n][kk] = *reinterpret_cast<const short8*>(
            Bc + row * 128 + ((kk * 64 + g * 16) ^ ((row & 7) << 4)));
    }
    #pragma unroll
    for (int kk = 0; kk < 2; ++kk)
      #pragma unroll
      for (int m = 0; m < 2; ++m)
        #pragma unroll
        for (int n = 0; n < 2; ++n)
          acc[m][n] = __builtin_amdgcn_mfma_f32_16x16x32_bf16(af[m][kk], bfr[n][kk], acc[m][n], 0, 0, 0);
    cur ^= 1;
  }

  #pragma unroll
  for (int n = 0; n < 2; ++n) {
    int col = bcol + wc * 32 + n * 16 + r;
    float bv = bias[col];
    #pragma unroll
    for (int m = 0; m < 2; ++m) {
      #pragma unroll
      for (int reg = 0; reg < 4; ++reg) {
        int row = brow + wr * 32 + m * 16 + g * 4 + reg;
        float v = acc[m][n][reg] + bv;
        if (OUT_BF16)
          ((unsigned short*)Cout)[(size_t)row * N + col] = f2bf(v * oscale);
        else
          ((float*)Cout)[(size_t)row * N + col] = v;
      }
    }
  }
}

// Flash attention (R17-verified skeleton + T5 setprio + single half-scale
// Q buffer). qhb = bf16(q*sqrt(c)), c = log2e/32: S = qhb.qhb = q.q*c exactly;
// V = transpose(qhb) carries sqrt(c), un-scaled in epilogue (inv = rsqc/l).
// Block = 8 waves = 4 q-subtiles(32 rows) x 2 kv-streams (exact split: no-max
// softmax is an order-free kv sum). Grid 512 (16 qtiles x 32 slabs), XCD
// swizzle; LDS 64KB -> 2 blocks/CU = 16 waves/CU.
__global__ __launch_bounds__(512) void attn_kernel(
    const unsigned short* __restrict__ qhb,
    const unsigned short* __restrict__ vtb,
    unsigned short* __restrict__ ob) {
  const int bid = blockIdx.x;            // 0..511
  const int xcd = bid & 7, idx = bid >> 3;   // idx 0..63
  const int slab = xcd * 4 + (idx >> 4);
  const int qtile = idx & 15;            // 128 q-rows per block
  const unsigned short* Qs = qhb + (size_t)slab * NS * HD;   // K and Q source
  const unsigned short* Vts = vtb + (size_t)slab * HD * NS;  // [64][2048] pi-perm
  unsigned short* Os = ob + (size_t)slab * NS * HD;
  const int tid = threadIdx.x;
  const int lane = tid & 63;
  const int wave = tid >> 6;             // 0..7
  const int qsub = wave >> 1;            // 0..3: which 32 q-rows
  const int h = wave & 1;                // 0/1: kv stream
  const int g = lane >> 4, r = lane & 15;
  const int qrow0 = qtile * 128 + qsub * 32;
  const int rkey = (r & 7) << 4;

  __shared__ __align__(16) unsigned short K_lds[2][2][KVBLK * HD];   // [h][buf]
  __shared__ __align__(16) unsigned short Vt_lds[2][2][HD * KVBLK];  // [h][buf]

  // stream h's tile t = global kv tile 2t+h; staged by the 4 waves of
  // stream h (2 gld16 per tensor per wave). Address math = R14 verbatim.
  auto stage = [&](int bb, int t) {
    int kt2 = 2 * t + h;
    const char* Kg = (const char*)Qs + (size_t)kt2 * 8192;   // 8KB K tile
    const char* Vg = (const char*)Vts + (size_t)kt2 * 128;   // col offset
    #pragma unroll
    for (int i = 0; i < 2; ++i) {
      int base = (qsub * 2 + i) * 1024;
      int L = base + lane * 16;
      int row = L >> 7, lsl = ((L >> 4) & 7) ^ (row & 7);
      gld16(Kg + row * 128 + lsl * 16, (char*)&K_lds[h][bb][0] + base);
      gld16(Vg + (size_t)row * (NS * 2) + lsl * 16, (char*)&Vt_lds[h][bb][0] + base);
    }
  };

  // Q fragments (half-scaled): B operand of swapped QK^T:
  // col q = qrow0 + m*16 + r, k d = kk*32 + g*8..+7
  short8 aq[2][2];
  #pragma unroll
  for (int m = 0; m < 2; ++m)
    #pragma unroll
    for (int kk = 0; kk < 2; ++kk)
      aq[m][kk] = *reinterpret_cast<const short8*>(
          &Qs[(size_t)(qrow0 + m * 16 + r) * HD + kk * 32 + g * 8]);

  const f32x4 zf = {0.f, 0.f, 0.f, 0.f};
  f32x4 o_acc[2][4];
  float l_lane[2] = {0.f, 0.f};          // partial l for q = m*16 + r
  #pragma unroll
  for (int m = 0; m < 2; ++m)
    #pragma unroll
    for (int n = 0; n < 4; ++n) o_acc[m][n] = zf;

  stage(0, 0);
  int cur = 0;
  for (int t = 0; t < NS / KVBLK / 2; ++t) {   // 16 iters per stream
    __syncthreads();                          // staged tiles visible
    if (t + 1 < NS / KVBLK / 2) stage(cur ^ 1, t + 1);
    const char* Kc = (const char*)&K_lds[h][cur][0];
    const char* Vc = (const char*)&Vt_lds[h][cur][0];

    // S^T = K Q^T : lane(g,r) gets S[kv=jb*16+g*4+reg][q=m*16+r]
    f32x4 s[2][4];
    __builtin_amdgcn_s_setprio(1);
    #pragma unroll
    for (int jb = 0; jb < 4; ++jb) {
      short8 bk[2];
      #pragma unroll
      for (int kk = 0; kk < 2; ++kk)
        bk[kk] = *reinterpret_cast<const short8*>(
            Kc + (jb * 16 + r) * 128 + ((kk * 64 + g * 16) ^ rkey));
      #pragma unroll
      for (int m = 0; m < 2; ++m) {
        s[m][jb] = zf;
        #pragma unroll
        for (int kk = 0; kk < 2; ++kk)
          s[m][jb] = __builtin_amdgcn_mfma_f32_16x16x32_bf16(bk[kk], aq[m][kk], s[m][jb], 0, 0, 0);
      }
    }
    __builtin_amdgcn_s_setprio(0);

    // p = 2^(s); row-sum into per-lane l; pack PV A-frags in-register:
    // ap[m][kk][j] = P[q=m*16+r][kv = kk*32 + (j>>2)*16 + g*4 + (j&3)]
    short8 ap[2][2];
    #pragma unroll
    for (int m = 0; m < 2; ++m) {
      float p[4][4];
      #pragma unroll
      for (int jb = 0; jb < 4; ++jb)
        #pragma unroll
        for (int reg = 0; reg < 4; ++reg)
          p[jb][reg] = __builtin_amdgcn_exp2f(s[m][jb][reg]);
      float t0 = (p[0][0] + p[0][1]) + (p[0][2] + p[0][3]);
      float t1 = (p[1][0] + p[1][1]) + (p[1][2] + p[1][3]);
      float t2 = (p[2][0] + p[2][1]) + (p[2][2] + p[2][3]);
      float t3 = (p[3][0] + p[3][1]) + (p[3][2] + p[3][3]);
      l_lane[m] += (t0 + t1) + (t2 + t3);
      #pragma unroll
      for (int kk = 0; kk < 2; ++kk) {
        u32x4 w;
        w.x = cvt_pk_bf16(p[2 * kk][0], p[2 * kk][1]);
        w.y = cvt_pk_bf16(p[2 * kk][2], p[2 * kk][3]);
        w.z = cvt_pk_bf16(p[2 * kk + 1][0], p[2 * kk + 1][1]);
        w.w = cvt_pk_bf16(p[2 * kk + 1][2], p[2 * kk + 1][3]);
        ap[m][kk] = __builtin_bit_cast(short8, w);
      }
    }

    // O += P V (pi order): B[k_pv][col=d] from Vt_lds rows n*16+r
    __builtin_amdgcn_s_setprio(1);
    #pragma unroll
    for (int n = 0; n < 4; ++n) {
      short8 bv[2];
      #pragma unroll
      for (int kk = 0; kk < 2; ++kk)
        bv[kk] = *reinterpret_cast<const short8*>(
            Vc + (n * 16 + r) * 128 + ((kk * 64 + g * 16) ^ rkey));
      #pragma unroll
      for (int m = 0; m < 2; ++m)
        #pragma unroll
        for (int kk = 0; kk < 2; ++kk)
          o_acc[m][n] = __builtin_amdgcn_mfma_f32_16x16x32_bf16(ap[m][kk], bv[kk], o_acc[m][n], 0, 0, 0);
    }
    __builtin_amdgcn_s_setprio(0);
    cur ^= 1;
  }

  // cross-stream reduction through the (now dead) staging LDS.
  __syncthreads();                       // all staging/compute complete
  char* redO = (char*)&K_lds[0][0][0];
  char* redL = (char*)&Vt_lds[0][0][0];
  if (h == 1) {
    #pragma unroll
    for (int m = 0; m < 2; ++m)
      #pragma unroll
      for (int n = 0; n < 4; ++n)
        *reinterpret_cast<f32x4*>(redO + qsub * 8192 + (m * 4 + n) * 1024 + lane * 16) = o_acc[m][n];
    float2 lp; lp.x = l_lane[0]; lp.y = l_lane[1];
    *reinterpret_cast<float2*>(redL + qsub * 512 + lane * 8) = lp;
  }
  __syncthreads();
  if (h == 0) {
    #pragma unroll
    for (int m = 0; m < 2; ++m)
      #pragma unroll
      for (int n = 0; n < 4; ++n)
        o_acc[m][n] += *reinterpret_cast<f32x4*>(
            redO + qsub * 8192 + (m * 4 + n) * 1024 + lane * 16);
    float2 lp = *reinterpret_cast<float2*>(redL + qsub * 512 + lane * 8);
    l_lane[0] += lp.x; l_lane[1] += lp.y;

    // epilogue: complete l across g-lanes, normalize, un-scale V's sqrt(c)
    const float rsqc = 1.0f / sqrtf(SEXP2);   // compile-time folded
    #pragma unroll
    for (int m = 0; m < 2; ++m) {
      float l = l_lane[m];
      l += __shfl_xor(l, 16);
      l += __shfl_xor(l, 32);                 // all lanes: full l[q=m*16+r]
      #pragma unroll
      for (int reg = 0; reg < 4; ++reg) {
        float inv = rsqc / __shfl(l, g * 4 + reg);
        int row = qrow0 + m * 16 + g * 4 + reg;
        #pragma unroll
        for (int n = 0; n < 4; ++n)
          Os[(size_t)row * HD + n * 16 + r] = f2bf(o_acc[m][n][reg] * inv);
      }
    }
  }
}

extern "C" void kernel_launch(void* const* d_in, const int* in_sizes, int n_in,
                              void* d_out, int out_size, void* d_ws, size_t ws_size,
                              hipStream_t stream) {
  const float* x  = (const float*)d_in[0];
  const float* wq = (const float*)d_in[1];
  const float* bq = (const float*)d_in[2];
  const float* wu = (const float*)d_in[3];
  const float* bu = (const float*)d_in[4];
  float* out = (float*)d_out;

  char* ws = (char*)d_ws;
  unsigned short* xb  = (unsigned short*)(ws);                 // 8 MB (reused as vtb)
  unsigned short* qhb = (unsigned short*)(ws + (8u  << 20));   // 8 MB: bf16(q*sqrt(c))
  unsigned short* ob  = (unsigned short*)(ws + (16u << 20));   // 8 MB: attn output
  unsigned short* wqb = (unsigned short*)(ws + (24u << 20));   // 2 MB
  unsigned short* wub = (unsigned short*)(ws + (26u << 20));   // 2 MB

  // all three f32->bf16 conversions in one launch
  const int nx = NTOK * EMB, nw = EMB * EMB;
  cvt_bf16x3_kernel<<<((nx + 2 * nw) / 8 + 255) / 256, 256, 0, stream>>>(
      x, xb, nx, wq, wqb, nw, wu, wub, nw);

  // q = x @ wq^T + bq -> qhb = bf16(q * sqrt(c)), single rounded
  gemm_bt_kernel<true><<<dim3(EMB / 64, NTOK / 64), 256, 0, stream>>>(
      xb, wqb, bq, qhb, sqrtf(SEXP2), NTOK, EMB, EMB);

  // xb is dead now; reuse as vtb: per-slab pi-permuted transpose of qhb
  unsigned short* vtb = xb;
  transpose_kernel<<<dim3(NS / 64, HEADS * NB), 256, 0, stream>>>(qhb, vtb);

  // 512 blocks (16 qtiles x 32 slabs) x 512 threads; XCD swizzle in-kernel
  attn_kernel<<<dim3(512), 512, 0, stream>>>(qhb, vtb, ob);

  // y = O @ wu^T + bu -> f32
  gemm_bt_kernel<false><<<dim3(EMB / 64, NTOK / 64), 256, 0, stream>>>(
      ob, wub, bu, out, 1.0f, NTOK, EMB, EMB);
}